// Round 11
// baseline (185.848 us; speedup 1.0000x reference)
//
#include <hip/hip_runtime.h>

#define DF 64
#define ELLK 32      // per-node ELL width; LDS ovl handles deg>32 exactly
#define BSH 9        // bucket = 512-node dst range
#define WIN 128      // nodes per fused block = quarter bucket = 8 MFMA tiles
#define CAP 32       // pairs slots per (bin-block, bucket) cell = one 128 B line
#define OCAP 32      // per-bin-block chunk-overflow entries (u64); exact fallback
#define WPAD 132     // Wl LDS row stride (bf16), de-banked
#define OVL 128      // per-window ELL-overflow capacity
#define MAXCH 800    // compile-time bound on bin-block count (actual ~782)

typedef __attribute__((ext_vector_type(8))) short bf16x8;  // MFMA A/B frag
typedef __attribute__((ext_vector_type(4))) float f32x4;   // MFMA C/D frag

__device__ __forceinline__ unsigned short bf16rne(float f) {
    unsigned u = __float_as_uint(f);
    unsigned r = u + 0x7fffu + ((u >> 16) & 1u);
    return (unsigned short)(r >> 16);
}
__device__ __forceinline__ float b2f(unsigned short u) {
    return __uint_as_float((unsigned)u << 16);
}

// ---------------------------------------------------------------------------
// K1 (fused conv + SINGLE-PASS bin), 512 thr x NCH blocks:
//  conv : h -> hbs bf16 [(N+1)][64] (row N = zero sentinel), W -> Wbs,
//         grid-strided.
//  bin  : VECTORIZED single pass -- int4 loads give each thread 4
//         independent {load -> LDS-atomic-rank -> chunk store} chains in
//         flight (EPB forced to a multiple of 4, 16 B aligned). Rank IS the
//         chunk slot: pairs[(bkt*NCH + blk)*CAP + r]; r >= CAP -> ovfb.
//         bcnt stored TRANSPOSED [NBK][NCH] for K2's coalesced read.
// ---------------------------------------------------------------------------
__global__ __launch_bounds__(512) void conv_bin(
    const float* __restrict__ h, const float* __restrict__ W,
    const int* __restrict__ src, const int* __restrict__ dst,
    unsigned short* __restrict__ hbs, unsigned short* __restrict__ Wbs,
    unsigned* __restrict__ pairs, int* __restrict__ bcnt,
    unsigned long long* __restrict__ ovfb, int* __restrict__ bovn,
    int N, int E, int NBK, int NCH, int EPB)
{
    __shared__ unsigned hist[256];
    __shared__ int ovn_l;
    const int t = threadIdx.x, blk = blockIdx.x;
    if (t < 256) hist[t] = 0;
    if (t == 0) ovn_l = 0;
    __syncthreads();

    // ---- conv (grid-stride): 1024 W chunks + (N+1)*8 h chunks ----
    int tot = 1024 + (N + 1) * 8;
    for (int i = blk * 512 + t; i < tot; i += NCH * 512) {
        if (i < 1024) {
            int row = i >> 4, c8 = i & 15;
            const float* wp = &W[(size_t)row * 128 + c8 * 8];
            float4 w0 = *(const float4*)wp;
            float4 w1 = *(const float4*)(wp + 4);
            bf16x8 f;
            f[0] = (short)bf16rne(w0.x); f[1] = (short)bf16rne(w0.y);
            f[2] = (short)bf16rne(w0.z); f[3] = (short)bf16rne(w0.w);
            f[4] = (short)bf16rne(w1.x); f[5] = (short)bf16rne(w1.y);
            f[6] = (short)bf16rne(w1.z); f[7] = (short)bf16rne(w1.w);
            *(bf16x8*)&Wbs[(size_t)row * 128 + c8 * 8] = f;
        } else {
            int j = i - 1024;
            int n = j >> 3, f8 = j & 7;
            unsigned short* op = &hbs[(size_t)n * DF + f8 * 8];
            if (n == N) {
                ushort4 z = {0, 0, 0, 0};
                *(ushort4*)op = z; *(ushort4*)(op + 4) = z;
            } else {
                const float* hp = &h[(size_t)n * DF + f8 * 8];
                float4 v0 = *(const float4*)hp;
                float4 v1 = *(const float4*)(hp + 4);
                ushort4 o0, o1;
                o0.x = bf16rne(v0.x); o0.y = bf16rne(v0.y);
                o0.z = bf16rne(v0.z); o0.w = bf16rne(v0.w);
                o1.x = bf16rne(v1.x); o1.y = bf16rne(v1.y);
                o1.z = bf16rne(v1.z); o1.w = bf16rne(v1.w);
                *(ushort4*)op = o0;
                *(ushort4*)(op + 4) = o1;
            }
        }
    }

    // ---- bin own edge range: 4 edges/thread via int4 (independent chains)
    int e0 = blk * EPB, e1 = e0 + EPB; if (e1 > E) e1 = E;
    int ne = e1 - e0;
    int nv = ne >> 2;   // int4 groups
    #define BIN1(d_, s_)                                                     \
        {                                                                    \
            unsigned bkt = (unsigned)(d_) >> BSH;                            \
            unsigned r = atomicAdd(&hist[bkt], 1u);                          \
            if (r < CAP) {                                                   \
                pairs[((size_t)bkt * NCH + blk) * CAP + r] =                 \
                    ((unsigned)((d_) & 511) << 17) | (unsigned)(s_);         \
            } else {                                                         \
                int p = atomicAdd(&ovn_l, 1);                                \
                if (p < OCAP)                                                \
                    ovfb[(size_t)blk * OCAP + p] =                           \
                        ((unsigned long long)(unsigned)(d_) << 32) |         \
                        (unsigned)(s_);                                      \
            }                                                                \
        }
    for (int g = t; g < nv; g += 512) {
        int4 d4 = *(const int4*)&dst[e0 + g * 4];
        int4 s4 = *(const int4*)&src[e0 + g * 4];
        BIN1(d4.x, s4.x); BIN1(d4.y, s4.y);
        BIN1(d4.z, s4.z); BIN1(d4.w, s4.w);
    }
    for (int e = e0 + (nv << 2) + t; e < e1; e += 512) {   // tail (<4 edges)
        int d = dst[e], s = src[e];
        BIN1(d, s);
    }
    #undef BIN1
    __syncthreads();
    for (int i = t; i < NBK; i += 512) {
        unsigned c = hist[i];
        bcnt[(size_t)i * NCH + blk] = (int)(c < CAP ? c : CAP);  // [NBK][NCH]
    }
    if (t == 0) bovn[blk] = (ovn_l < OCAP ? ovn_l : OCAP);
}

// ---------------------------------------------------------------------------
// K2 (fused build + gather + MFMA update) — R10 structure, gather phase now
// 2-NODE INTERLEAVED: issue node A's and node B's gathers (up to 8 loads in
// flight), reduce A (VALU overlaps B's loads returning), reduce B.
// Block = 128-node window, 512 thr, LDS ~37.6 KB -> 4 blocks/CU.
// ---------------------------------------------------------------------------
__global__ __launch_bounds__(512, 8) void gather_update(
    const unsigned* __restrict__ pairs, const int* __restrict__ bcnt,
    const unsigned long long* __restrict__ ovfb, const int* __restrict__ bovn,
    const unsigned short* __restrict__ hbs, const unsigned short* __restrict__ Wbs,
    const float* __restrict__ h, const float* __restrict__ b,
    float* __restrict__ out, int N, int NBK, int NCH)
{
    __shared__ int ell_l[WIN * ELLK];          // 16 KB; reused as csum rows
    __shared__ int cnt_l[WIN];                 // 0.5 KB
    __shared__ unsigned short Wl[64 * WPAD];   // 16.9 KB
    __shared__ int bcnt_l[MAXCH];              // 3.2 KB
    __shared__ int ovl[OVL * 2];               // 1 KB
    __shared__ int ovn;

    const int t = threadIdx.x, lane = t & 63, wv = t >> 6;
    const int base = blockIdx.x * WIN;
    const int bk = base >> BSH;
    const int q0 = base & 511;

    for (int i = t; i < WIN; i += 512) cnt_l[i] = 0;
    if (t == 0) ovn = 0;
    for (int i = t; i < 1024; i += 512) {   // W -> LDS (padded)
        int row = i >> 4, c8 = i & 15;
        *(bf16x8*)&Wl[row * WPAD + c8 * 8] =
            *(const bf16x8*)&Wbs[(size_t)row * 128 + c8 * 8];
    }
    for (int i = t; i < NCH; i += 512)
        bcnt_l[i] = bcnt[(size_t)bk * NCH + i];   // coalesced (transposed layout)
    __syncthreads();

    // ---- build: 2 chunks per wave-iter (32-lane halves match CAP=32) ----
    int nit = (NCH + 15) >> 4;
    for (int it = 0; it < nit; ++it) {
        int ch = it * 16 + wv * 2 + (lane >> 5);
        int slot = lane & 31;
        if (ch < NCH && slot < bcnt_l[ch]) {
            unsigned p = pairs[((size_t)bk * NCH + ch) * CAP + slot];
            int ld = (int)(p >> 17) - q0;
            if ((unsigned)ld < (unsigned)WIN) {
                int s = (int)(p & 131071u);
                int sl2 = atomicAdd(&cnt_l[ld], 1);
                if (sl2 < ELLK) {
                    ell_l[ld * ELLK + (((sl2 & 7) << 2) | (sl2 >> 3))] = s;
                } else {
                    int q2 = atomicAdd(&ovn, 1);
                    if (q2 < OVL) { ovl[2 * q2] = ld; ovl[2 * q2 + 1] = s; }
                }
            }
        }
    }
    // chunk-capacity overflow rescan (~always empty)
    for (int i = t; i < NCH; i += 512) {
        int bn = bovn[i];
        for (int j = 0; j < bn; ++j) {
            unsigned long long v = ovfb[(size_t)i * OCAP + j];
            int d = (int)(v >> 32);
            int ld = d - base;
            if ((unsigned)ld < (unsigned)WIN) {
                int s = (int)(v & 0xFFFFFFFFu);
                int sl2 = atomicAdd(&cnt_l[ld], 1);
                if (sl2 < ELLK) {
                    ell_l[ld * ELLK + (((sl2 & 7) << 2) | (sl2 >> 3))] = s;
                } else {
                    int q2 = atomicAdd(&ovn, 1);
                    if (q2 < OVL) { ovl[2 * q2] = ld; ovl[2 * q2 + 1] = s; }
                }
            }
        }
    }
    __syncthreads();

    // ---- gather: wave wv owns nodes [wv*16, wv*16+16), 2-node interleave --
    unsigned short* csB = (unsigned short*)ell_l;   // reuse: sum rows
    {
        const int ew = lane >> 3;   // neighbor slot within quad (0..7)
        const int f8 = lane & 7;    // 16 B feat chunk of the 128 B row

        #define GLOAD(n_, ld_, m_, ms_, v0_, v1_, v2_, v3_)                    \
            if ((n_) < N) {                                                    \
                int cv = cnt_l[ld_];                                           \
                m_ = cv < ELLK ? cv : ELLK;                                    \
                ms_ = __builtin_amdgcn_readfirstlane(m_);                      \
                int4 pv = ((const int4*)&ell_l[(ld_) * ELLK])[ew];             \
                int i0 = (ew     < m_) ? pv.x : N;                             \
                int i1 = (ew + 8 < m_) ? pv.y : N;                             \
                v0_ = *(const bf16x8*)&hbs[(size_t)i0 * DF + f8 * 8];          \
                v1_ = *(const bf16x8*)&hbs[(size_t)i1 * DF + f8 * 8];          \
                if (ms_ > 16) {                                                \
                    int i2 = (ew + 16 < m_) ? pv.z : N;                        \
                    v2_ = *(const bf16x8*)&hbs[(size_t)i2 * DF + f8 * 8];      \
                    if (ms_ > 24) {                                            \
                        int i3 = (ew + 24 < m_) ? pv.w : N;                    \
                        v3_ = *(const bf16x8*)&hbs[(size_t)i3 * DF + f8 * 8];  \
                    }                                                          \
                }                                                              \
            }

        #define GREDUCE(ld_, v0_, v1_, v2_, v3_)                               \
            {                                                                  \
                float a[8];                                                    \
                _Pragma("unroll")                                              \
                for (int j = 0; j < 8; ++j)                                    \
                    a[j] = (b2f((unsigned short)v0_[j]) +                      \
                            b2f((unsigned short)v1_[j]))                       \
                         + (b2f((unsigned short)v2_[j]) +                      \
                            b2f((unsigned short)v3_[j]));                      \
                _Pragma("unroll")                                              \
                for (int msk = 8; msk <= 32; msk <<= 1) {                      \
                    _Pragma("unroll")                                          \
                    for (int j = 0; j < 8; ++j) a[j] += __shfl_xor(a[j], msk); \
                }                                                              \
                if (ew == 0) {                                                 \
                    bf16x8 o;                                                  \
                    _Pragma("unroll")                                          \
                    for (int j = 0; j < 8; ++j) o[j] = (short)bf16rne(a[j]);   \
                    int sl = f8 ^ ((ld_) & 7);                                 \
                    *(bf16x8*)&csB[(ld_) * 64 + sl * 8] = o;                   \
                }                                                              \
            }

        for (int i = 0; i < 16; i += 2) {
            int ldA = wv * 16 + i, ldB = ldA + 1;
            int nA = base + ldA,   nB = base + ldB;
            int mA = 0, msA = 0, mB = 0, msB = 0;
            bf16x8 vA0 = {0,0,0,0,0,0,0,0}, vA1 = {0,0,0,0,0,0,0,0};
            bf16x8 vA2 = {0,0,0,0,0,0,0,0}, vA3 = {0,0,0,0,0,0,0,0};
            bf16x8 vB0 = {0,0,0,0,0,0,0,0}, vB1 = {0,0,0,0,0,0,0,0};
            bf16x8 vB2 = {0,0,0,0,0,0,0,0}, vB3 = {0,0,0,0,0,0,0,0};
            GLOAD(nA, ldA, mA, msA, vA0, vA1, vA2, vA3);   // issue A loads
            GLOAD(nB, ldB, mB, msB, vB0, vB1, vB2, vB3);   // issue B loads
            GREDUCE(ldA, vA0, vA1, vA2, vA3);              // overlaps B loads
            GREDUCE(ldB, vB0, vB1, vB2, vB3);
        }
        #undef GLOAD
        #undef GREDUCE
    }
    __syncthreads();

    // ---- update: wave wv -> tile nodes [wv*16, wv*16+16) ----
    const int c = lane & 15, q = lane >> 4;
    float bias[4];
    #pragma unroll
    for (int nt = 0; nt < 4; ++nt) bias[nt] = b[nt * 16 + c];

    int ovnc = ovn; if (ovnc > OVL) ovnc = OVL;

    int wn0 = wv * 16;
    int nm = base + wn0 + c;
    int nmc = nm < N ? nm : N - 1;
    int dtot = cnt_l[wn0 + c];                 // TRUE degree
    float inv = 1.0f / fmaxf((float)dtot, 1.0f);

    bf16x8 a0 = *(const bf16x8*)&hbs[(size_t)nmc * DF + q * 8];
    bf16x8 a1 = *(const bf16x8*)&hbs[(size_t)nmc * DF + 32 + q * 8];
    bf16x8 a2, a3;
    #pragma unroll
    for (int kc = 0; kc < 2; ++kc) {
        int srow = wn0 + c;
        int sl = (kc * 4 + q) ^ (srow & 7);    // inverse of the write swizzle
        bf16x8 u = *(const bf16x8*)&csB[srow * 64 + sl * 8];
        float e[8];
        #pragma unroll
        for (int i = 0; i < 8; ++i) e[i] = b2f((unsigned short)u[i]);
        if (ovnc > 0) {
            for (int t2 = 0; t2 < ovnc; ++t2) {
                if (ovl[2 * t2] == wn0 + c) {  // deg>32 extras (counted in dtot)
                    bf16x8 hu = *(const bf16x8*)&hbs[(size_t)ovl[2 * t2 + 1] * DF + kc * 32 + q * 8];
                    #pragma unroll
                    for (int i = 0; i < 8; ++i) e[i] += b2f((unsigned short)hu[i]);
                }
            }
        }
        bf16x8 f;
        #pragma unroll
        for (int i = 0; i < 8; ++i) f[i] = (short)bf16rne(e[i] * inv);
        if (kc == 0) a2 = f; else a3 = f;
    }

    #define WF(nt, kt) (*(const bf16x8*)&Wl[((nt) * 16 + c) * WPAD + (kt) * 32 + q * 8])
    f32x4 acc0 = {bias[0], bias[0], bias[0], bias[0]};
    f32x4 acc1 = {bias[1], bias[1], bias[1], bias[1]};
    f32x4 acc2 = {bias[2], bias[2], bias[2], bias[2]};
    f32x4 acc3 = {bias[3], bias[3], bias[3], bias[3]};
    acc0 = __builtin_amdgcn_mfma_f32_16x16x32_bf16(a0, WF(0,0), acc0, 0, 0, 0);
    acc0 = __builtin_amdgcn_mfma_f32_16x16x32_bf16(a1, WF(0,1), acc0, 0, 0, 0);
    acc0 = __builtin_amdgcn_mfma_f32_16x16x32_bf16(a2, WF(0,2), acc0, 0, 0, 0);
    acc0 = __builtin_amdgcn_mfma_f32_16x16x32_bf16(a3, WF(0,3), acc0, 0, 0, 0);
    acc1 = __builtin_amdgcn_mfma_f32_16x16x32_bf16(a0, WF(1,0), acc1, 0, 0, 0);
    acc1 = __builtin_amdgcn_mfma_f32_16x16x32_bf16(a1, WF(1,1), acc1, 0, 0, 0);
    acc1 = __builtin_amdgcn_mfma_f32_16x16x32_bf16(a2, WF(1,2), acc1, 0, 0, 0);
    acc1 = __builtin_amdgcn_mfma_f32_16x16x32_bf16(a3, WF(1,3), acc1, 0, 0, 0);
    acc2 = __builtin_amdgcn_mfma_f32_16x16x32_bf16(a0, WF(2,0), acc2, 0, 0, 0);
    acc2 = __builtin_amdgcn_mfma_f32_16x16x32_bf16(a1, WF(2,1), acc2, 0, 0, 0);
    acc2 = __builtin_amdgcn_mfma_f32_16x16x32_bf16(a2, WF(2,2), acc2, 0, 0, 0);
    acc2 = __builtin_amdgcn_mfma_f32_16x16x32_bf16(a3, WF(2,3), acc2, 0, 0, 0);
    acc3 = __builtin_amdgcn_mfma_f32_16x16x32_bf16(a0, WF(3,0), acc3, 0, 0, 0);
    acc3 = __builtin_amdgcn_mfma_f32_16x16x32_bf16(a1, WF(3,1), acc3, 0, 0, 0);
    acc3 = __builtin_amdgcn_mfma_f32_16x16x32_bf16(a2, WF(3,2), acc3, 0, 0, 0);
    acc3 = __builtin_amdgcn_mfma_f32_16x16x32_bf16(a3, WF(3,3), acc3, 0, 0, 0);
    #undef WF

    float ss[4];
    #pragma unroll
    for (int r = 0; r < 4; ++r)
        ss[r] = acc0[r] * acc0[r] + acc1[r] * acc1[r]
              + acc2[r] * acc2[r] + acc3[r] * acc3[r];
    #pragma unroll
    for (int msk = 1; msk <= 8; msk <<= 1) {
        ss[0] += __shfl_xor(ss[0], msk);
        ss[1] += __shfl_xor(ss[1], msk);
        ss[2] += __shfl_xor(ss[2], msk);
        ss[3] += __shfl_xor(ss[3], msk);
    }
    #pragma unroll
    for (int r = 0; r < 4; ++r) {
        int nr = base + wn0 + q * 4 + r;
        int dr = __shfl(dtot, q * 4 + r);
        if (nr < N) {
            float rin = 1.0f / fmaxf(sqrtf(ss[r]), 1e-12f);
            const float* hp = &h[(size_t)nr * DF + c];
            float hv0 = hp[0], hv1 = hp[16], hv2 = hp[32], hv3 = hp[48];
            bool up = dr > 0;
            float o0 = hv0 + (up ? fmaxf(acc0[r] * rin, 0.f) : hv0);
            float o1 = hv1 + (up ? fmaxf(acc1[r] * rin, 0.f) : hv1);
            float o2 = hv2 + (up ? fmaxf(acc2[r] * rin, 0.f) : hv2);
            float o3 = hv3 + (up ? fmaxf(acc3[r] * rin, 0.f) : hv3);
            float* op = &out[(size_t)nr * DF + c];
            op[0] = o0; op[16] = o1; op[32] = o2; op[48] = o3;
        }
    }
}

extern "C" void kernel_launch(void* const* d_in, const int* in_sizes, int n_in,
                              void* d_out, int out_size, void* d_ws, size_t ws_size,
                              hipStream_t stream) {
    const float* h   = (const float*)d_in[0];
    const float* W   = (const float*)d_in[1];
    const float* b   = (const float*)d_in[2];
    const int*   src = (const int*)d_in[3];
    const int*   dst = (const int*)d_in[4];
    float* out = (float*)d_out;

    const int N = in_sizes[0] / DF;
    const int E = in_sizes[3];
    const int NBK = (N + 511) >> BSH;                  // 196
    int NCH = (E + 2047) / 2048;                       // ~782 bin blocks
    if (NCH > MAXCH) NCH = MAXCH;
    int EPB = ((E + NCH - 1) / NCH + 3) & ~3;          // multiple of 4 (int4)

    // workspace carve (16B-aligned); no pre-zeroing needed
    unsigned short* Wbs = (unsigned short*)d_ws;                       // 64*128
    unsigned short* hbs = Wbs + 64 * 128;                              // (N+1)*64
    unsigned* pairs = (unsigned*)(hbs + (((size_t)(N + 1) * DF + 15) & ~(size_t)15));
    int* bcnt = (int*)(pairs + (size_t)NBK * NCH * CAP);               // [NBK][NCH]
    int* bovn = bcnt + (((size_t)NBK * NCH + 15) & ~(size_t)15);       // NCH
    unsigned long long* ovfb =
        (unsigned long long*)(bovn + ((NCH + 15) & ~15));              // NCH*OCAP

    // K1: fused bf16 conversions + vectorized single-pass edge binning
    conv_bin<<<NCH, 512, 0, stream>>>(
        h, W, src, dst, hbs, Wbs, pairs, bcnt, ovfb, bovn, N, E, NBK, NCH, EPB);

    // K2: fused build + gather (2-node interleaved) + MFMA update
    gather_update<<<(N + WIN - 1) / WIN, 512, 0, stream>>>(
        pairs, bcnt, ovfb, bovn, hbs, Wbs, h, b, out, N, NBK, NCH);
}

// Round 13
// 172.805 us; speedup vs baseline: 1.0755x; 1.0755x over previous
//
#include <hip/hip_runtime.h>

#define DF 64
#define ELLK 32      // per-node ELL width; LDS ovl handles deg>32 exactly
#define BSH 9        // bucket = 512-node dst range
#define WIN 128      // nodes per fused block = quarter bucket = 8 MFMA tiles
#define CAP 32       // pairs slots per (bin-block, bucket) cell = one 128 B line
#define OCAP 32      // per-bin-block chunk-overflow entries (u64); exact fallback
#define WPAD 132     // Wl LDS row stride (bf16), de-banked
#define OVL 128      // per-window ELL-overflow capacity
#define MAXCH 800    // compile-time bound on bin-block count (actual ~782)

typedef __attribute__((ext_vector_type(8))) short bf16x8;  // MFMA A/B frag
typedef __attribute__((ext_vector_type(4))) float f32x4;   // MFMA C/D frag

__device__ __forceinline__ unsigned short bf16rne(float f) {
    unsigned u = __float_as_uint(f);
    unsigned r = u + 0x7fffu + ((u >> 16) & 1u);
    return (unsigned short)(r >> 16);
}
__device__ __forceinline__ float b2f(unsigned short u) {
    return __uint_as_float((unsigned)u << 16);
}

// ---------------------------------------------------------------------------
// K1 (fused conv + SINGLE-PASS bin), 512 thr x NCH blocks — R10 verbatim.
//  conv : h -> hbs bf16 [(N+1)][64] (row N = zero sentinel), W -> Wbs,
//         grid-strided.
//  bin  : one pass over own edge range; the LDS-histogram rank IS the chunk
//         slot: pairs[(bkt*NCH + blk)*CAP + r]. r >= CAP -> per-block ovfb
//         (u64 d<<32|src). bcnt stored TRANSPOSED [NBK][NCH] so K2's read
//         is coalesced. No pre-zeroed global state needed.
// ---------------------------------------------------------------------------
__global__ __launch_bounds__(512) void conv_bin(
    const float* __restrict__ h, const float* __restrict__ W,
    const int* __restrict__ src, const int* __restrict__ dst,
    unsigned short* __restrict__ hbs, unsigned short* __restrict__ Wbs,
    unsigned* __restrict__ pairs, int* __restrict__ bcnt,
    unsigned long long* __restrict__ ovfb, int* __restrict__ bovn,
    int N, int E, int NBK, int NCH, int EPB)
{
    __shared__ unsigned hist[256];
    __shared__ int ovn_l;
    const int t = threadIdx.x, blk = blockIdx.x;
    if (t < 256) hist[t] = 0;
    if (t == 0) ovn_l = 0;
    __syncthreads();

    // ---- conv (grid-stride): 1024 W chunks + (N+1)*8 h chunks ----
    int tot = 1024 + (N + 1) * 8;
    for (int i = blk * 512 + t; i < tot; i += NCH * 512) {
        if (i < 1024) {
            int row = i >> 4, c8 = i & 15;
            const float* wp = &W[(size_t)row * 128 + c8 * 8];
            float4 w0 = *(const float4*)wp;
            float4 w1 = *(const float4*)(wp + 4);
            bf16x8 f;
            f[0] = (short)bf16rne(w0.x); f[1] = (short)bf16rne(w0.y);
            f[2] = (short)bf16rne(w0.z); f[3] = (short)bf16rne(w0.w);
            f[4] = (short)bf16rne(w1.x); f[5] = (short)bf16rne(w1.y);
            f[6] = (short)bf16rne(w1.z); f[7] = (short)bf16rne(w1.w);
            *(bf16x8*)&Wbs[(size_t)row * 128 + c8 * 8] = f;
        } else {
            int j = i - 1024;
            int n = j >> 3, f8 = j & 7;
            unsigned short* op = &hbs[(size_t)n * DF + f8 * 8];
            if (n == N) {
                ushort4 z = {0, 0, 0, 0};
                *(ushort4*)op = z; *(ushort4*)(op + 4) = z;
            } else {
                const float* hp = &h[(size_t)n * DF + f8 * 8];
                float4 v0 = *(const float4*)hp;
                float4 v1 = *(const float4*)(hp + 4);
                ushort4 o0, o1;
                o0.x = bf16rne(v0.x); o0.y = bf16rne(v0.y);
                o0.z = bf16rne(v0.z); o0.w = bf16rne(v0.w);
                o1.x = bf16rne(v1.x); o1.y = bf16rne(v1.y);
                o1.z = bf16rne(v1.z); o1.w = bf16rne(v1.w);
                *(ushort4*)op = o0;
                *(ushort4*)(op + 4) = o1;
            }
        }
    }

    // ---- bin own edge range, single pass (rank = chunk slot) ----
    int e0 = blk * EPB, e1 = e0 + EPB; if (e1 > E) e1 = E;
    for (int e = e0 + t; e < e1; e += 512) {
        int d = dst[e], s = src[e];
        unsigned bkt = (unsigned)d >> BSH;
        unsigned r = atomicAdd(&hist[bkt], 1u);
        if (r < CAP) {
            pairs[((size_t)bkt * NCH + blk) * CAP + r] =
                ((unsigned)(d & 511) << 17) | (unsigned)s;
        } else {   // chunk overflow -> exact per-block list
            int p = atomicAdd(&ovn_l, 1);
            if (p < OCAP)
                ovfb[(size_t)blk * OCAP + p] =
                    ((unsigned long long)(unsigned)d << 32) | (unsigned)s;
        }
    }
    __syncthreads();
    for (int i = t; i < NBK; i += 512) {
        unsigned c = hist[i];
        bcnt[(size_t)i * NCH + blk] = (int)(c < CAP ? c : CAP);  // [NBK][NCH]
    }
    if (t == 0) bovn[blk] = (ovn_l < OCAP ? ovn_l : OCAP);
}

// ---------------------------------------------------------------------------
// K2 (fused build + gather + MFMA update) — R10 verbatim except the
// epilogue residual now reads hbs (bf16, L1-warm: same rows as a0/a1)
// instead of the f32 h array, deleting a 25.6 MB cold stream.
// Block = 128-node window, 512 thr, LDS ~37.6 KB -> 4 blocks/CU.
// ---------------------------------------------------------------------------
__global__ __launch_bounds__(512, 8) void gather_update(
    const unsigned* __restrict__ pairs, const int* __restrict__ bcnt,
    const unsigned long long* __restrict__ ovfb, const int* __restrict__ bovn,
    const unsigned short* __restrict__ hbs, const unsigned short* __restrict__ Wbs,
    const float* __restrict__ b,
    float* __restrict__ out, int N, int NBK, int NCH)
{
    __shared__ int ell_l[WIN * ELLK];          // 16 KB; reused as csum rows
    __shared__ int cnt_l[WIN];                 // 0.5 KB
    __shared__ unsigned short Wl[64 * WPAD];   // 16.9 KB
    __shared__ int bcnt_l[MAXCH];              // 3.2 KB
    __shared__ int ovl[OVL * 2];               // 1 KB
    __shared__ int ovn;

    const int t = threadIdx.x, lane = t & 63, wv = t >> 6;
    const int base = blockIdx.x * WIN;
    const int bk = base >> BSH;
    const int q0 = base & 511;

    for (int i = t; i < WIN; i += 512) cnt_l[i] = 0;
    if (t == 0) ovn = 0;
    for (int i = t; i < 1024; i += 512) {   // W -> LDS (padded)
        int row = i >> 4, c8 = i & 15;
        *(bf16x8*)&Wl[row * WPAD + c8 * 8] =
            *(const bf16x8*)&Wbs[(size_t)row * 128 + c8 * 8];
    }
    for (int i = t; i < NCH; i += 512)
        bcnt_l[i] = bcnt[(size_t)bk * NCH + i];   // coalesced (transposed layout)
    __syncthreads();

    // ---- build: 2 chunks per wave-iter (32-lane halves match CAP=32) ----
    int nit = (NCH + 15) >> 4;   // 16 chunks per block-iter (2/wave x 8 waves)
    for (int it = 0; it < nit; ++it) {
        int ch = it * 16 + wv * 2 + (lane >> 5);
        int slot = lane & 31;
        if (ch < NCH && slot < bcnt_l[ch]) {
            unsigned p = pairs[((size_t)bk * NCH + ch) * CAP + slot];
            int ld = (int)(p >> 17) - q0;
            if ((unsigned)ld < (unsigned)WIN) {
                int s = (int)(p & 131071u);
                int sl2 = atomicAdd(&cnt_l[ld], 1);
                if (sl2 < ELLK) {
                    ell_l[ld * ELLK + (((sl2 & 7) << 2) | (sl2 >> 3))] = s;
                } else {
                    int q2 = atomicAdd(&ovn, 1);
                    if (q2 < OVL) { ovl[2 * q2] = ld; ovl[2 * q2 + 1] = s; }
                }
            }
        }
    }
    // chunk-capacity overflow rescan (~always empty)
    for (int i = t; i < NCH; i += 512) {
        int bn = bovn[i];
        for (int j = 0; j < bn; ++j) {
            unsigned long long v = ovfb[(size_t)i * OCAP + j];
            int d = (int)(v >> 32);
            int ld = d - base;
            if ((unsigned)ld < (unsigned)WIN) {
                int s = (int)(v & 0xFFFFFFFFu);
                int sl2 = atomicAdd(&cnt_l[ld], 1);
                if (sl2 < ELLK) {
                    ell_l[ld * ELLK + (((sl2 & 7) << 2) | (sl2 >> 3))] = s;
                } else {
                    int q2 = atomicAdd(&ovn, 1);
                    if (q2 < OVL) { ovl[2 * q2] = ld; ovl[2 * q2 + 1] = s; }
                }
            }
        }
    }
    __syncthreads();

    // ---- gather: wave wv owns nodes [wv*16, wv*16+16) ----
    unsigned short* csB = (unsigned short*)ell_l;   // reuse: sum rows
    {
        const int ew = lane >> 3;   // neighbor slot within quad (0..7)
        const int f8 = lane & 7;    // 16 B feat chunk of the 128 B row
        for (int i = 0; i < 16; ++i) {
            int ld = wv * 16 + i;
            int n = base + ld;
            if (n < N) {
                int cv = cnt_l[ld];
                int m = cv < ELLK ? cv : ELLK;
                int ms = __builtin_amdgcn_readfirstlane(m);
                int4 pv = ((const int4*)&ell_l[ld * ELLK])[ew];  // read BEFORE write-back

                int i0 = (ew     < m) ? pv.x : N;
                int i1 = (ew + 8 < m) ? pv.y : N;
                bf16x8 v0 = *(const bf16x8*)&hbs[(size_t)i0 * DF + f8 * 8];
                bf16x8 v1 = *(const bf16x8*)&hbs[(size_t)i1 * DF + f8 * 8];
                bf16x8 v2 = {0,0,0,0,0,0,0,0};
                bf16x8 v3 = {0,0,0,0,0,0,0,0};
                if (ms > 16) {   // skipped for ~57% of nodes
                    int i2 = (ew + 16 < m) ? pv.z : N;
                    v2 = *(const bf16x8*)&hbs[(size_t)i2 * DF + f8 * 8];
                    if (ms > 24) {   // skipped for ~93% of nodes
                        int i3 = (ew + 24 < m) ? pv.w : N;
                        v3 = *(const bf16x8*)&hbs[(size_t)i3 * DF + f8 * 8];
                    }
                }

                float a[8];
                #pragma unroll
                for (int j = 0; j < 8; ++j)
                    a[j] = (b2f((unsigned short)v0[j]) + b2f((unsigned short)v1[j]))
                         + (b2f((unsigned short)v2[j]) + b2f((unsigned short)v3[j]));
                #pragma unroll
                for (int msk = 8; msk <= 32; msk <<= 1) {
                    #pragma unroll
                    for (int j = 0; j < 8; ++j) a[j] += __shfl_xor(a[j], msk);
                }
                if (ew == 0) {   // write-back into own row, slot-swizzled
                    bf16x8 o;
                    #pragma unroll
                    for (int j = 0; j < 8; ++j) o[j] = (short)bf16rne(a[j]);
                    int sl = f8 ^ (ld & 7);
                    *(bf16x8*)&csB[ld * 64 + sl * 8] = o;
                }
            } else if (ew == 0) {   // zero-fill invalid node rows
                bf16x8 z = {0,0,0,0,0,0,0,0};
                int sl = f8 ^ (ld & 7);
                *(bf16x8*)&csB[ld * 64 + sl * 8] = z;
            }
        }
    }
    __syncthreads();

    // ---- update: wave wv -> tile nodes [wv*16, wv*16+16) ----
    const int c = lane & 15, q = lane >> 4;
    float bias[4];
    #pragma unroll
    for (int nt = 0; nt < 4; ++nt) bias[nt] = b[nt * 16 + c];

    int ovnc = ovn; if (ovnc > OVL) ovnc = OVL;

    int wn0 = wv * 16;
    int nm = base + wn0 + c;
    int nmc = nm < N ? nm : N - 1;
    int dtot = cnt_l[wn0 + c];                 // TRUE degree
    float inv = 1.0f / fmaxf((float)dtot, 1.0f);

    bf16x8 a0 = *(const bf16x8*)&hbs[(size_t)nmc * DF + q * 8];
    bf16x8 a1 = *(const bf16x8*)&hbs[(size_t)nmc * DF + 32 + q * 8];
    bf16x8 a2, a3;
    #pragma unroll
    for (int kc = 0; kc < 2; ++kc) {
        int srow = wn0 + c;
        int sl = (kc * 4 + q) ^ (srow & 7);    // inverse of the write swizzle
        bf16x8 u = *(const bf16x8*)&csB[srow * 64 + sl * 8];
        float e[8];
        #pragma unroll
        for (int i = 0; i < 8; ++i) e[i] = b2f((unsigned short)u[i]);
        if (ovnc > 0) {
            for (int t2 = 0; t2 < ovnc; ++t2) {
                if (ovl[2 * t2] == wn0 + c) {  // deg>32 extras (counted in dtot)
                    bf16x8 hu = *(const bf16x8*)&hbs[(size_t)ovl[2 * t2 + 1] * DF + kc * 32 + q * 8];
                    #pragma unroll
                    for (int i = 0; i < 8; ++i) e[i] += b2f((unsigned short)hu[i]);
                }
            }
        }
        bf16x8 f;
        #pragma unroll
        for (int i = 0; i < 8; ++i) f[i] = (short)bf16rne(e[i] * inv);
        if (kc == 0) a2 = f; else a3 = f;
    }

    #define WF(nt, kt) (*(const bf16x8*)&Wl[((nt) * 16 + c) * WPAD + (kt) * 32 + q * 8])
    f32x4 acc0 = {bias[0], bias[0], bias[0], bias[0]};
    f32x4 acc1 = {bias[1], bias[1], bias[1], bias[1]};
    f32x4 acc2 = {bias[2], bias[2], bias[2], bias[2]};
    f32x4 acc3 = {bias[3], bias[3], bias[3], bias[3]};
    acc0 = __builtin_amdgcn_mfma_f32_16x16x32_bf16(a0, WF(0,0), acc0, 0, 0, 0);
    acc0 = __builtin_amdgcn_mfma_f32_16x16x32_bf16(a1, WF(0,1), acc0, 0, 0, 0);
    acc0 = __builtin_amdgcn_mfma_f32_16x16x32_bf16(a2, WF(0,2), acc0, 0, 0, 0);
    acc0 = __builtin_amdgcn_mfma_f32_16x16x32_bf16(a3, WF(0,3), acc0, 0, 0, 0);
    acc1 = __builtin_amdgcn_mfma_f32_16x16x32_bf16(a0, WF(1,0), acc1, 0, 0, 0);
    acc1 = __builtin_amdgcn_mfma_f32_16x16x32_bf16(a1, WF(1,1), acc1, 0, 0, 0);
    acc1 = __builtin_amdgcn_mfma_f32_16x16x32_bf16(a2, WF(1,2), acc1, 0, 0, 0);
    acc1 = __builtin_amdgcn_mfma_f32_16x16x32_bf16(a3, WF(1,3), acc1, 0, 0, 0);
    acc2 = __builtin_amdgcn_mfma_f32_16x16x32_bf16(a0, WF(2,0), acc2, 0, 0, 0);
    acc2 = __builtin_amdgcn_mfma_f32_16x16x32_bf16(a1, WF(2,1), acc2, 0, 0, 0);
    acc2 = __builtin_amdgcn_mfma_f32_16x16x32_bf16(a2, WF(2,2), acc2, 0, 0, 0);
    acc2 = __builtin_amdgcn_mfma_f32_16x16x32_bf16(a3, WF(2,3), acc2, 0, 0, 0);
    acc3 = __builtin_amdgcn_mfma_f32_16x16x32_bf16(a0, WF(3,0), acc3, 0, 0, 0);
    acc3 = __builtin_amdgcn_mfma_f32_16x16x32_bf16(a1, WF(3,1), acc3, 0, 0, 0);
    acc3 = __builtin_amdgcn_mfma_f32_16x16x32_bf16(a2, WF(3,2), acc3, 0, 0, 0);
    acc3 = __builtin_amdgcn_mfma_f32_16x16x32_bf16(a3, WF(3,3), acc3, 0, 0, 0);
    #undef WF

    float ss[4];
    #pragma unroll
    for (int r = 0; r < 4; ++r)
        ss[r] = acc0[r] * acc0[r] + acc1[r] * acc1[r]
              + acc2[r] * acc2[r] + acc3[r] * acc3[r];
    #pragma unroll
    for (int msk = 1; msk <= 8; msk <<= 1) {
        ss[0] += __shfl_xor(ss[0], msk);
        ss[1] += __shfl_xor(ss[1], msk);
        ss[2] += __shfl_xor(ss[2], msk);
        ss[3] += __shfl_xor(ss[3], msk);
    }
    #pragma unroll
    for (int r = 0; r < 4; ++r) {
        int nr = base + wn0 + q * 4 + r;
        int dr = __shfl(dtot, q * 4 + r);
        if (nr < N) {
            float rin = 1.0f / fmaxf(sqrtf(ss[r]), 1e-12f);
            // residual from hbs (bf16, L1-warm; same rows as a0/a1 loads)
            const unsigned short* hp = &hbs[(size_t)nr * DF + c];
            float hv0 = b2f(hp[0]),  hv1 = b2f(hp[16]);
            float hv2 = b2f(hp[32]), hv3 = b2f(hp[48]);
            bool up = dr > 0;
            float o0 = hv0 + (up ? fmaxf(acc0[r] * rin, 0.f) : hv0);
            float o1 = hv1 + (up ? fmaxf(acc1[r] * rin, 0.f) : hv1);
            float o2 = hv2 + (up ? fmaxf(acc2[r] * rin, 0.f) : hv2);
            float o3 = hv3 + (up ? fmaxf(acc3[r] * rin, 0.f) : hv3);
            float* op = &out[(size_t)nr * DF + c];
            op[0] = o0; op[16] = o1; op[32] = o2; op[48] = o3;
        }
    }
}

extern "C" void kernel_launch(void* const* d_in, const int* in_sizes, int n_in,
                              void* d_out, int out_size, void* d_ws, size_t ws_size,
                              hipStream_t stream) {
    const float* h   = (const float*)d_in[0];
    const float* W   = (const float*)d_in[1];
    const float* b   = (const float*)d_in[2];
    const int*   src = (const int*)d_in[3];
    const int*   dst = (const int*)d_in[4];
    float* out = (float*)d_out;

    const int N = in_sizes[0] / DF;
    const int E = in_sizes[3];
    const int NBK = (N + 511) >> BSH;                  // 196
    int NCH = (E + 2047) / 2048;                       // ~782 bin blocks
    if (NCH > MAXCH) NCH = MAXCH;
    const int EPB = (E + NCH - 1) / NCH;               // ~2048 edges/block

    // workspace carve (16B-aligned); no pre-zeroing needed
    unsigned short* Wbs = (unsigned short*)d_ws;                       // 64*128
    unsigned short* hbs = Wbs + 64 * 128;                              // (N+1)*64
    unsigned* pairs = (unsigned*)(hbs + (((size_t)(N + 1) * DF + 15) & ~(size_t)15));
    int* bcnt = (int*)(pairs + (size_t)NBK * NCH * CAP);               // [NBK][NCH]
    int* bovn = bcnt + (((size_t)NBK * NCH + 15) & ~(size_t)15);       // NCH
    unsigned long long* ovfb =
        (unsigned long long*)(bovn + ((NCH + 15) & ~15));              // NCH*OCAP

    // K1: fused bf16 conversions + single-pass edge binning
    conv_bin<<<NCH, 512, 0, stream>>>(
        h, W, src, dst, hbs, Wbs, pairs, bcnt, ovfb, bovn, N, E, NBK, NCH, EPB);

    // K2: fused build + gather + MFMA update (782 blocks, 4/CU, no tail)
    gather_update<<<(N + WIN - 1) / WIN, 512, 0, stream>>>(
        pairs, bcnt, ovfb, bovn, hbs, Wbs, b, out, N, NBK, NCH);
}